// Round 1
// baseline (60.946 us; speedup 1.0000x reference)
//
#include <hip/hip_runtime.h>
#include <math.h>

#define BN 1024
#define CN 10
#define DN 16
#define NE1 16
#define NE2 136
#define NE3 816
#define NE4 3876
#define NENT 4844   // 16+136+816+3876 sorted tuples
#define EB 19       // ceil(4844/256) entry-blocks per cluster
#define CH 256      // member chunk staged in LDS
#define EPSV 1e-7f

__device__ __forceinline__ int H2f(int n){ return n*(n+1)/2; }
__device__ __forceinline__ int H3f(int n){ return n*(n+1)*(n+2)/6; }

__device__ __forceinline__ int rank2f(int i,int j){
  int r=0;
  for(int a=0;a<i;a++) r += (DN-a);
  return r + (j-i);
}
__device__ __forceinline__ int rank3f(int i,int j,int k){
  int r=0;
  for(int a=0;a<i;a++) r += H2f(DN-a);
  for(int b=i;b<j;b++) r += (DN-b);
  return r + (k-j);
}
__device__ __forceinline__ int rank4f(int i,int j,int k,int l){
  int r=0;
  for(int a=0;a<i;a++) r += H3f(DN-a);
  for(int b=i;b<j;b++) r += H2f(DN-b);
  for(int c=j;c<k;c++) r += (DN-c);
  return r + (l-k);
}

// signed compressive roots (match reference params exactly)
__device__ __forceinline__ float sroot2f(float x){
  float s = (x<0.f)?-1.f:1.f;
  return s*(sqrtf(fabsf(x)+0.25f)-0.5f);
}
__device__ __forceinline__ float sroot3f(float x){
  float s=(x<0.f)?-1.f:1.f;
  return s*(cbrtf(fabsf(x)+0.19245008973f)-0.57735026919f);
}
__device__ __forceinline__ float sroot4f(float x){
  float s=(x<0.f)?-1.f:1.f;
  return s*(sqrtf(sqrtf(fabsf(x)+0.15749013123f))-0.62996052494f);
}

__device__ __forceinline__ unsigned packe(int i,int j,int k,int l,int o){
  return (unsigned)(i | (j<<5) | (k<<10) | (l<<15) | (o<<20));
}

// Kernel A: argmax assignment + per-cluster compaction + entry table build.
__global__ __launch_bounds__(1024) void ka(
    const float* __restrict__ logits,
    const float* __restrict__ gm1, const float* __restrict__ gm2,
    const float* __restrict__ gm3, const float* __restrict__ gm4,
    unsigned* __restrict__ table, float* __restrict__ targ,
    int* __restrict__ counts, int* __restrict__ idxlist) {
  int tid = threadIdx.x;
  __shared__ int cnt[CN];
  if (tid < CN) cnt[tid] = 0;
  __syncthreads();

  // --- assignment + compaction (thread tid == sample tid; BN==1024) ---
  {
    const float* lr = logits + tid*CN;
    float best = lr[0]; int bi = 0;
    #pragma unroll
    for (int c=1;c<CN;c++){ float v=lr[c]; if (v>best){best=v;bi=c;} }  // first-max like jnp.argmax
    int slot = atomicAdd(&cnt[bi],1);
    idxlist[bi*BN + slot] = tid;
  }

  // --- entry table: order 1 ---
  if (tid < NE1) {
    table[tid] = packe(tid,16,16,16,1);
    targ[tid]  = gm1[tid];                 // no sroot for order 1
  }
  // --- order 2: scan raw 16x16 ---
  if (tid < 256) {
    int i = tid>>4, j = tid&15;
    if (i<=j) {
      int r = NE1 + rank2f(i,j);
      table[r] = packe(i,j,16,16,2);
      targ[r]  = sroot2f(gm2[tid]);
    }
  }
  // --- order 3: scan raw 16^3 ---
  for (int t=tid; t<4096; t+=1024) {
    int i=(t>>8)&15, j=(t>>4)&15, k=t&15;
    if (i<=j && j<=k) {
      int r = NE1 + NE2 + rank3f(i,j,k);
      table[r] = packe(i,j,k,16,3);
      targ[r]  = sroot3f(gm3[t]);
    }
  }
  // --- order 4: scan raw 16^4 ---
  for (int t=tid; t<65536; t+=1024) {
    int i=(t>>12)&15, j=(t>>8)&15, k=(t>>4)&15, l=t&15;
    if (i<=j && j<=k && k<=l) {
      int r = NE1 + NE2 + NE3 + rank4f(i,j,k,l);
      table[r] = packe(i,j,k,l,4);
      targ[r]  = sroot4f(gm4[t]);
    }
  }
  __syncthreads();
  if (tid < CN) counts[tid] = cnt[tid];
}

// Kernel B: per (cluster, entry-chunk) block, accumulate moment entries and
// the weighted squared penalty contribution.
__global__ __launch_bounds__(256) void kb(
    const float* __restrict__ emb, const float* __restrict__ centers,
    const unsigned* __restrict__ table, const float* __restrict__ targ,
    const int* __restrict__ counts, const int* __restrict__ idxlist,
    float* __restrict__ partials) {
  // transposed diff tile: sx[i][n], stride 257 -> bank (i+n)%32 (conflict-free)
  // row 16 holds 1.0f so every entry is a uniform 4-factor product.
  __shared__ float sx[17][CH+1];
  __shared__ float red[256];
  int tid = threadIdx.x;
  int c  = blockIdx.x / EB;
  int eb = blockIdx.x % EB;
  int cnt = counts[c];

  for (int n=tid; n<CH+1; n+=256) sx[16][n] = 1.f;

  int e = eb*256 + tid;
  int ii=16, jj=16, kk=16, ll=16, order=1;
  float tg = 0.f;
  bool valid = (e < NENT);
  if (valid) {
    unsigned p = table[e];
    ii = p&31; jj = (p>>5)&31; kk = (p>>10)&31; ll = (p>>15)&31;
    order = (p>>20)&7;
    tg = targ[e];
  }

  float acc = 0.f;
  for (int base=0; base<cnt; base+=CH) {
    int m = min(CH, cnt-base);
    __syncthreads();              // protect previous chunk (and ones row, 1st iter)
    if (tid < m) {
      int b = idxlist[c*BN + base + tid];
      const float4* er = (const float4*)(emb + b*DN);
      const float4* cr = (const float4*)(centers + c*DN);
      float4 e0=er[0], e1=er[1], e2=er[2], e3=er[3];
      float4 c0=cr[0], c1=cr[1], c2=cr[2], c3=cr[3];
      float v[16];
      v[0]=e0.x-c0.x; v[1]=e0.y-c0.y; v[2]=e0.z-c0.z; v[3]=e0.w-c0.w;
      v[4]=e1.x-c1.x; v[5]=e1.y-c1.y; v[6]=e1.z-c1.z; v[7]=e1.w-c1.w;
      v[8]=e2.x-c2.x; v[9]=e2.y-c2.y; v[10]=e2.z-c2.z; v[11]=e2.w-c2.w;
      v[12]=e3.x-c3.x; v[13]=e3.y-c3.y; v[14]=e3.z-c3.z; v[15]=e3.w-c3.w;
      #pragma unroll
      for (int i=0;i<16;i++) sx[i][tid] = v[i];
    }
    __syncthreads();
    for (int n=0; n<m; n++) {
      acc += sx[ii][n]*sx[jj][n]*sx[kk][n]*sx[ll][n];
    }
  }

  float contrib = 0.f;
  if (valid) {
    float mval = acc;
    if (order <= 2) mval /= ((float)cnt + EPSV);
    float v;
    if      (order==1) v = mval - tg;
    else if (order==2) v = sroot2f(mval) - tg;
    else if (order==3) v = sroot3f(mval) - tg;
    else               v = sroot4f(mval) - tg;
    float lw = (order==1)?1.f:(order==2)?0.5f:(order==3)?0.25f:0.125f;
    float cwn = (float)cnt * (1.f/1024.f);   // sum(cw) == B exactly
    contrib = lw * cwn * v * v;
  }

  red[tid] = contrib;
  __syncthreads();
  for (int s=128; s>0; s>>=1) {
    if (tid < s) red[tid] += red[tid+s];
    __syncthreads();
  }
  if (tid==0) partials[blockIdx.x] = red[0];
}

// Kernel C: final reduce of 190 partials -> scalar.
__global__ __launch_bounds__(256) void kc(const float* __restrict__ partials,
                                          float* __restrict__ out) {
  __shared__ float red[256];
  int tid = threadIdx.x;
  float s = 0.f;
  for (int i=tid; i<CN*EB; i+=256) s += partials[i];
  red[tid] = s;
  __syncthreads();
  for (int k=128; k>0; k>>=1) {
    if (tid < k) red[tid] += red[tid+k];
    __syncthreads();
  }
  if (tid==0) out[0] = red[0];
}

extern "C" void kernel_launch(void* const* d_in, const int* in_sizes, int n_in,
                              void* d_out, int out_size, void* d_ws, size_t ws_size,
                              hipStream_t stream) {
  const float* emb  = (const float*)d_in[0];   // [1024,16]
  const float* cen  = (const float*)d_in[1];   // [10,16]
  const float* logi = (const float*)d_in[2];   // [1024,10]
  const float* gm1  = (const float*)d_in[3];   // [16]
  const float* gm2  = (const float*)d_in[4];   // [16,16]
  const float* gm3  = (const float*)d_in[5];   // [16^3]
  const float* gm4  = (const float*)d_in[6];   // [16^4]
  // mw1..mw4 (d_in[7..10]) unused: mw[tuple] * #perms(tuple) == 1 exactly.

  unsigned* table   = (unsigned*)d_ws;                 // [NENT]
  float*    targ    = (float*)d_ws + NENT;             // [NENT]
  int*      counts  = (int*)d_ws + 2*NENT;             // [CN]
  int*      idxlist = counts + CN;                     // [CN*BN]
  float*    partials= (float*)(idxlist + CN*BN);       // [CN*EB]

  ka<<<1, 1024, 0, stream>>>(logi, gm1, gm2, gm3, gm4, table, targ, counts, idxlist);
  kb<<<CN*EB, 256, 0, stream>>>(emb, cen, table, targ, counts, idxlist, partials);
  kc<<<1, 256, 0, stream>>>(partials, (float*)d_out);
}

// Round 2
// 20.594 us; speedup vs baseline: 2.9593x; 2.9593x over previous
//
#include <hip/hip_runtime.h>
#include <math.h>

#define BN 1024
#define CN 10
#define DN 16
#define NE1 16
#define NE2 136
#define NE3 816
#define NE4 3876
#define NENT 4844   // 16+136+816+3876 sorted tuples
#define EB 19       // ceil(4844/256) entry-blocks per cluster
#define CH 256      // member chunk staged in LDS
#define EPSV 1e-7f

__device__ __forceinline__ int H2f(int n){ return n*(n+1)/2; }
__device__ __forceinline__ int H3f(int n){ return n*(n+1)*(n+2)/6; }

// signed compressive roots (match reference params exactly)
__device__ __forceinline__ float sroot2f(float x){
  float s = (x<0.f)?-1.f:1.f;
  return s*(sqrtf(fabsf(x)+0.25f)-0.5f);
}
__device__ __forceinline__ float sroot3f(float x){
  float s=(x<0.f)?-1.f:1.f;
  return s*(cbrtf(fabsf(x)+0.19245008973f)-0.57735026919f);
}
__device__ __forceinline__ float sroot4f(float x){
  float s=(x<0.f)?-1.f:1.f;
  return s*(sqrtf(sqrtf(fabsf(x)+0.15749013123f))-0.62996052494f);
}

// Kernel A: argmax assignment + deterministic ballot-based compaction.
// Also zeroes the cross-block accumulator + ticket for kernel B.
__global__ __launch_bounds__(1024) void ka(
    const float* __restrict__ logits,
    int* __restrict__ counts, int* __restrict__ idxlist,
    float* __restrict__ acc, int* __restrict__ ticket) {
  int tid  = threadIdx.x;
  int lane = tid & 63;
  int wave = tid >> 6;          // 16 waves
  if (tid == 0) { acc[0] = 0.f; ticket[0] = 0; }

  const float* lr = logits + tid*CN;
  float best = lr[0]; int bi = 0;
  #pragma unroll
  for (int c=1;c<CN;c++){ float v=lr[c]; if (v>best){best=v;bi=c;} }  // first-max like jnp.argmax

  __shared__ int wcnt[16][CN];
  int lanerank = 0;
  #pragma unroll
  for (int c=0;c<CN;c++){
    unsigned long long m = __ballot(bi==c);
    if (bi==c) lanerank = __popcll(m & ((1ull<<lane)-1ull));
    if (lane==0) wcnt[wave][c] = __popcll(m);
  }
  __syncthreads();
  int off = 0;
  for (int w=0; w<wave; w++) off += wcnt[w][bi];
  idxlist[bi*BN + off + lanerank] = tid;

  if (tid < CN) {
    int t = 0;
    #pragma unroll
    for (int w=0; w<16; w++) t += wcnt[w][tid];
    counts[tid] = t;
  }
}

// Kernel B: per (cluster, entry-chunk) block. Each thread unranks its sorted
// tuple, accumulates the 4-factor product over cluster members from LDS,
// applies sroot + target + weights, block-reduces, then atomically combines
// across blocks; last block writes the scalar output.
__global__ __launch_bounds__(256) void kb(
    const float* __restrict__ emb, const float* __restrict__ centers,
    const float* __restrict__ gm1, const float* __restrict__ gm2,
    const float* __restrict__ gm3, const float* __restrict__ gm4,
    const int* __restrict__ counts, const int* __restrict__ idxlist,
    float* __restrict__ acc, int* __restrict__ ticket,
    float* __restrict__ out) {
  // transposed diff tile: sx[i][n], stride 257 -> bank (i+n)%32 (conflict-free)
  // row 16 holds 1.0f so every entry is a uniform 4-factor product.
  __shared__ float sx[17][CH+1];
  __shared__ float red[256];
  int tid = threadIdx.x;
  int c  = blockIdx.x / EB;
  int eb = blockIdx.x % EB;
  int cnt = counts[c];

  for (int n=tid; n<CH+1; n+=256) sx[16][n] = 1.f;

  // --- unrank entry e -> sorted tuple (ii<=jj<=kk<=ll), order, target ---
  int e = eb*256 + tid;
  int ii=16, jj=16, kk=16, ll=16, order=1;
  float tg = 0.f;
  bool valid = (e < NENT);
  if (valid) {
    if (e < NE1) {
      order=1; ii=e;
      tg = gm1[ii];                               // no sroot for order 1
    } else if (e < NE1+NE2) {
      order=2; int r = e-NE1;
      int i=0; while (r >= DN-i){ r -= DN-i; i++; }
      ii=i; jj=i+r;
      tg = sroot2f(gm2[ii*DN+jj]);
    } else if (e < NE1+NE2+NE3) {
      order=3; int r = e-(NE1+NE2);
      int i=0; while (r >= H2f(DN-i)){ r -= H2f(DN-i); i++; }
      int j=i; while (r >= DN-j){ r -= DN-j; j++; }
      ii=i; jj=j; kk=j+r;
      tg = sroot3f(gm3[(ii*DN+jj)*DN+kk]);
    } else {
      order=4; int r = e-(NE1+NE2+NE3);
      int i=0; while (r >= H3f(DN-i)){ r -= H3f(DN-i); i++; }
      int j=i; while (r >= H2f(DN-j)){ r -= H2f(DN-j); j++; }
      int k=j; while (r >= DN-k){ r -= DN-k; k++; }
      ii=i; jj=j; kk=k; ll=k+r;
      tg = sroot4f(gm4[((ii*DN+jj)*DN+kk)*DN+ll]);
    }
  }

  float mom = 0.f;
  for (int base=0; base<cnt; base+=CH) {
    int m = min(CH, cnt-base);
    __syncthreads();              // protect previous chunk (and ones row, 1st iter)
    if (tid < m) {
      int b = idxlist[c*BN + base + tid];
      const float4* er = (const float4*)(emb + b*DN);
      const float4* cr = (const float4*)(centers + c*DN);
      float4 e0=er[0], e1=er[1], e2=er[2], e3=er[3];
      float4 c0=cr[0], c1=cr[1], c2=cr[2], c3=cr[3];
      float v[16];
      v[0]=e0.x-c0.x; v[1]=e0.y-c0.y; v[2]=e0.z-c0.z; v[3]=e0.w-c0.w;
      v[4]=e1.x-c1.x; v[5]=e1.y-c1.y; v[6]=e1.z-c1.z; v[7]=e1.w-c1.w;
      v[8]=e2.x-c2.x; v[9]=e2.y-c2.y; v[10]=e2.z-c2.z; v[11]=e2.w-c2.w;
      v[12]=e3.x-c3.x; v[13]=e3.y-c3.y; v[14]=e3.z-c3.z; v[15]=e3.w-c3.w;
      #pragma unroll
      for (int i=0;i<16;i++) sx[i][tid] = v[i];
    }
    __syncthreads();
    for (int n=0; n<m; n++) {
      mom += sx[ii][n]*sx[jj][n]*sx[kk][n]*sx[ll][n];
    }
  }

  float contrib = 0.f;
  if (valid) {
    float mval = mom;
    if (order <= 2) mval /= ((float)cnt + EPSV);
    float v;
    if      (order==1) v = mval - tg;
    else if (order==2) v = sroot2f(mval) - tg;
    else if (order==3) v = sroot3f(mval) - tg;
    else               v = sroot4f(mval) - tg;
    float lw = (order==1)?1.f:(order==2)?0.5f:(order==3)?0.25f:0.125f;
    float cwn = (float)cnt * (1.f/1024.f);   // sum(cw) == B exactly
    contrib = lw * cwn * v * v;
  }

  red[tid] = contrib;
  __syncthreads();
  for (int s=128; s>0; s>>=1) {
    if (tid < s) red[tid] += red[tid+s];
    __syncthreads();
  }
  if (tid==0) {
    atomicAdd(acc, red[0]);
    __threadfence();
    int old = atomicAdd(ticket, 1);
    if (old == (int)gridDim.x - 1) {
      // all blocks' adds are visible (their fence preceded the ticket inc)
      float total = atomicAdd(acc, 0.0f);   // device-scope read
      out[0] = total;
    }
  }
}

extern "C" void kernel_launch(void* const* d_in, const int* in_sizes, int n_in,
                              void* d_out, int out_size, void* d_ws, size_t ws_size,
                              hipStream_t stream) {
  const float* emb  = (const float*)d_in[0];   // [1024,16]
  const float* cen  = (const float*)d_in[1];   // [10,16]
  const float* logi = (const float*)d_in[2];   // [1024,10]
  const float* gm1  = (const float*)d_in[3];   // [16]
  const float* gm2  = (const float*)d_in[4];   // [16,16]
  const float* gm3  = (const float*)d_in[5];   // [16^3]
  const float* gm4  = (const float*)d_in[6];   // [16^4]
  // mw1..mw4 (d_in[7..10]) unused: mw[tuple] * #perms(tuple) == 1 exactly.

  int*   counts  = (int*)d_ws;                 // [CN]
  int*   idxlist = counts + CN;                // [CN*BN]
  float* acc     = (float*)(idxlist + CN*BN);  // [1]
  int*   ticket  = (int*)(acc + 1);            // [1]

  ka<<<1, 1024, 0, stream>>>(logi, counts, idxlist, acc, ticket);
  kb<<<CN*EB, 256, 0, stream>>>(emb, cen, gm1, gm2, gm3, gm4,
                                counts, idxlist, acc, ticket, (float*)d_out);
}

// Round 3
// 18.993 us; speedup vs baseline: 3.2088x; 1.0843x over previous
//
#include <hip/hip_runtime.h>
#include <math.h>

#define BN 1024
#define CN 10
#define DN 16
#define NE1 16
#define NE2 136
#define NE3 816
#define NE4 3876
#define NENT 4844   // 16+136+816+3876 sorted tuples
#define EB 19       // ceil(4844/256) entry-blocks per cluster
#define CH 256      // member chunk staged in LDS
#define EPSV 1e-7f

__device__ __forceinline__ int H2f(int n){ return n*(n+1)/2; }
__device__ __forceinline__ int H3f(int n){ return n*(n+1)*(n+2)/6; }

// signed compressive roots (match reference params exactly)
__device__ __forceinline__ float sroot2f(float x){
  float s = (x<0.f)?-1.f:1.f;
  return s*(sqrtf(fabsf(x)+0.25f)-0.5f);
}
__device__ __forceinline__ float sroot3f(float x){
  float s=(x<0.f)?-1.f:1.f;
  return s*(cbrtf(fabsf(x)+0.19245008973f)-0.57735026919f);
}
__device__ __forceinline__ float sroot4f(float x){
  float s=(x<0.f)?-1.f:1.f;
  return s*(sqrtf(sqrtf(fabsf(x)+0.15749013123f))-0.62996052494f);
}

// Single fused kernel: each block = (cluster c, entry-chunk eb).
// The block redundantly recomputes the argmax assignment for all 1024 samples
// (L2-resident logits, ~4 argmaxes/thread) and compacts ITS cluster's member
// list into LDS with deterministic ballot ranking. Then each thread unranks
// its sorted moment tuple, accumulates the 4-factor product over members
// staged chunk-wise in a conflict-free transposed LDS tile, applies
// sroot/target/weights, block-reduces, and atomicAdds into out[0]
// (out is memset to 0 on the stream before launch).
__global__ __launch_bounds__(256) void kb(
    const float* __restrict__ emb, const float* __restrict__ centers,
    const float* __restrict__ logits,
    const float* __restrict__ gm1, const float* __restrict__ gm2,
    const float* __restrict__ gm3, const float* __restrict__ gm4,
    float* __restrict__ out) {
  // transposed diff tile: sx[i][n], stride 257 -> bank (i+n)%32 (conflict-free)
  // row 16 holds 1.0f so every entry is a uniform 4-factor product.
  __shared__ float sx[17][CH+1];
  __shared__ float red[256];
  __shared__ int   memb[BN];
  __shared__ int   wcnt[4][4];   // [round][wave]
  int tid  = threadIdx.x;
  int lane = tid & 63;
  int wave = tid >> 6;           // 4 waves
  int c  = blockIdx.x / EB;
  int eb = blockIdx.x % EB;

  for (int n=tid; n<CH+1; n+=256) sx[16][n] = 1.f;

  // --- assignment + per-cluster compaction (samples in ascending order) ---
  int rank_r[4]; bool match_r[4];
  #pragma unroll
  for (int r=0;r<4;r++) {
    int b = r*256 + tid;
    const float* lr = logits + b*CN;
    float best = lr[0]; int bi = 0;
    #pragma unroll
    for (int q=1;q<CN;q++){ float v=lr[q]; if (v>best){best=v;bi=q;} }  // first-max like jnp.argmax
    unsigned long long m = __ballot(bi==c);
    match_r[r] = (bi==c);
    rank_r[r] = __popcll(m & ((1ull<<lane)-1ull));
    if (lane==0) wcnt[r][wave] = __popcll(m);
  }
  __syncthreads();
  int pre[17]; pre[0]=0;
  #pragma unroll
  for (int p=0;p<16;p++) pre[p+1] = pre[p] + wcnt[p>>2][p&3];
  int cnt = pre[16];
  #pragma unroll
  for (int r=0;r<4;r++)
    if (match_r[r]) memb[pre[r*4+wave] + rank_r[r]] = r*256 + tid;

  // --- unrank entry e -> sorted tuple (ii<=jj<=kk<=ll), order, target ---
  int e = eb*256 + tid;
  int ii=16, jj=16, kk=16, ll=16, order=1;
  float tg = 0.f;
  bool valid = (e < NENT);
  if (valid) {
    if (e < NE1) {
      order=1; ii=e;
      tg = gm1[ii];                               // no sroot for order 1
    } else if (e < NE1+NE2) {
      order=2; int r = e-NE1;
      int i=0; while (r >= DN-i){ r -= DN-i; i++; }
      ii=i; jj=i+r;
      tg = sroot2f(gm2[ii*DN+jj]);
    } else if (e < NE1+NE2+NE3) {
      order=3; int r = e-(NE1+NE2);
      int i=0; while (r >= H2f(DN-i)){ r -= H2f(DN-i); i++; }
      int j=i; while (r >= DN-j){ r -= DN-j; j++; }
      ii=i; jj=j; kk=j+r;
      tg = sroot3f(gm3[(ii*DN+jj)*DN+kk]);
    } else {
      order=4; int r = e-(NE1+NE2+NE3);
      int i=0; while (r >= H3f(DN-i)){ r -= H3f(DN-i); i++; }
      int j=i; while (r >= H2f(DN-j)){ r -= H2f(DN-j); j++; }
      int k=j; while (r >= DN-k){ r -= DN-k; k++; }
      ii=i; jj=j; kk=k; ll=k+r;
      tg = sroot4f(gm4[((ii*DN+jj)*DN+kk)*DN+ll]);
    }
  }

  float mom = 0.f;
  for (int base=0; base<cnt; base+=CH) {
    int m = min(CH, cnt-base);
    __syncthreads();              // protects memb (1st iter) / previous chunk
    if (tid < m) {
      int b = memb[base + tid];
      const float4* er = (const float4*)(emb + b*DN);
      const float4* cr = (const float4*)(centers + c*DN);
      float4 e0=er[0], e1=er[1], e2=er[2], e3=er[3];
      float4 c0=cr[0], c1=cr[1], c2=cr[2], c3=cr[3];
      float v[16];
      v[0]=e0.x-c0.x; v[1]=e0.y-c0.y; v[2]=e0.z-c0.z; v[3]=e0.w-c0.w;
      v[4]=e1.x-c1.x; v[5]=e1.y-c1.y; v[6]=e1.z-c1.z; v[7]=e1.w-c1.w;
      v[8]=e2.x-c2.x; v[9]=e2.y-c2.y; v[10]=e2.z-c2.z; v[11]=e2.w-c2.w;
      v[12]=e3.x-c3.x; v[13]=e3.y-c3.y; v[14]=e3.z-c3.z; v[15]=e3.w-c3.w;
      #pragma unroll
      for (int i=0;i<16;i++) sx[i][tid] = v[i];
    }
    __syncthreads();
    for (int n=0; n<m; n++) {
      mom += sx[ii][n]*sx[jj][n]*sx[kk][n]*sx[ll][n];
    }
  }

  float contrib = 0.f;
  if (valid) {
    float mval = mom;
    if (order <= 2) mval /= ((float)cnt + EPSV);
    float v;
    if      (order==1) v = mval - tg;
    else if (order==2) v = sroot2f(mval) - tg;
    else if (order==3) v = sroot3f(mval) - tg;
    else               v = sroot4f(mval) - tg;
    float lw = (order==1)?1.f:(order==2)?0.5f:(order==3)?0.25f:0.125f;
    float cwn = (float)cnt * (1.f/1024.f);   // sum(cw) == B exactly
    contrib = lw * cwn * v * v;
  }

  red[tid] = contrib;
  __syncthreads();
  for (int s=128; s>0; s>>=1) {
    if (tid < s) red[tid] += red[tid+s];
    __syncthreads();
  }
  if (tid==0) atomicAdd(out, red[0]);   // out zeroed on stream before launch
}

extern "C" void kernel_launch(void* const* d_in, const int* in_sizes, int n_in,
                              void* d_out, int out_size, void* d_ws, size_t ws_size,
                              hipStream_t stream) {
  const float* emb  = (const float*)d_in[0];   // [1024,16]
  const float* cen  = (const float*)d_in[1];   // [10,16]
  const float* logi = (const float*)d_in[2];   // [1024,10]
  const float* gm1  = (const float*)d_in[3];   // [16]
  const float* gm2  = (const float*)d_in[4];   // [16,16]
  const float* gm3  = (const float*)d_in[5];   // [16^3]
  const float* gm4  = (const float*)d_in[6];   // [16^4]
  // mw1..mw4 (d_in[7..10]) unused: mw[tuple] * #perms(tuple) == 1 exactly.

  hipMemsetAsync(d_out, 0, sizeof(float), stream);   // graph-capturable memset node
  kb<<<CN*EB, 256, 0, stream>>>(emb, cen, logi, gm1, gm2, gm3, gm4, (float*)d_out);
}

// Round 4
// 18.112 us; speedup vs baseline: 3.3649x; 1.0486x over previous
//
#include <hip/hip_runtime.h>
#include <math.h>

#define BN 1024
#define CN 10
#define DN 16
#define NE1 16
#define NE2 136
#define NE3 816
#define NE4 3876
#define NENT 4844   // 16+136+816+3876 sorted tuples
#define EB 19       // ceil(4844/256) entry-blocks per cluster
#define CH 256      // member chunk staged in LDS
#define SST 260     // LDS row stride (floats): %4==0 for float4, banks pair only 2-way
#define EPSV 1e-7f

__device__ __forceinline__ int H2f(int n){ return n*(n+1)/2; }
__device__ __forceinline__ int H3f(int n){ return n*(n+1)*(n+2)/6; }

// signed compressive roots (match reference params exactly)
__device__ __forceinline__ float sroot2f(float x){
  float s = (x<0.f)?-1.f:1.f;
  return s*(sqrtf(fabsf(x)+0.25f)-0.5f);
}
__device__ __forceinline__ float sroot3f(float x){
  float s=(x<0.f)?-1.f:1.f;
  return s*(cbrtf(fabsf(x)+0.19245008973f)-0.57735026919f);
}
__device__ __forceinline__ float sroot4f(float x){
  float s=(x<0.f)?-1.f:1.f;
  return s*(sqrtf(sqrtf(fabsf(x)+0.15749013123f))-0.62996052494f);
}

// Single fused kernel: block = (cluster c, entry-chunk eb). Redundant per-block
// argmax assignment + ballot compaction into LDS; per-thread tuple unranking;
// member diffs staged in a component-major LDS tile (stride 260 -> float4 rows,
// 2-way-max bank aliasing = free); per-order float4 inner loops; wave-shuffle
// reduce; atomicAdd into out[0] (memset to 0 on stream before launch).
__global__ __launch_bounds__(256) void kb(
    const float* __restrict__ emb, const float* __restrict__ centers,
    const float* __restrict__ logits,
    const float* __restrict__ gm1, const float* __restrict__ gm2,
    const float* __restrict__ gm3, const float* __restrict__ gm4,
    float* __restrict__ out) {
  __shared__ float sx[DN][SST];
  __shared__ int   memb[BN];
  __shared__ int   wcnt[4][4];   // [round][wave]
  __shared__ float wred[4];
  int tid  = threadIdx.x;
  int lane = tid & 63;
  int wave = tid >> 6;           // 4 waves
  int c  = blockIdx.x / EB;
  int eb = blockIdx.x % EB;

  // --- assignment ballots (samples in ascending order) ---
  int rank_r[4]; bool match_r[4];
  #pragma unroll
  for (int r=0;r<4;r++) {
    int b = r*256 + tid;
    const float* lr = logits + b*CN;
    float best = lr[0]; int bi = 0;
    #pragma unroll
    for (int q=1;q<CN;q++){ float v=lr[q]; if (v>best){best=v;bi=q;} }  // first-max like jnp.argmax
    unsigned long long m = __ballot(bi==c);
    match_r[r] = (bi==c);
    rank_r[r] = __popcll(m & ((1ull<<lane)-1ull));
    if (lane==0) wcnt[r][wave] = __popcll(m);
  }

  // --- unrank entry e -> sorted tuple (ii<=jj<=kk<=ll), order, target ---
  // (placed before the sync so the scattered gm load latency overlaps)
  int e = eb*256 + tid;
  int ii=0, jj=0, kk=0, ll=0, order=0;
  float tg = 0.f;
  bool valid = (e < NENT);
  if (valid) {
    if (e < NE1) {
      order=1; ii=e;
      tg = gm1[ii];                               // no sroot for order 1
    } else if (e < NE1+NE2) {
      order=2; int r = e-NE1;
      int i=0; while (r >= DN-i){ r -= DN-i; i++; }
      ii=i; jj=i+r;
      tg = sroot2f(gm2[ii*DN+jj]);
    } else if (e < NE1+NE2+NE3) {
      order=3; int r = e-(NE1+NE2);
      int i=0; while (r >= H2f(DN-i)){ r -= H2f(DN-i); i++; }
      int j=i; while (r >= DN-j){ r -= DN-j; j++; }
      ii=i; jj=j; kk=j+r;
      tg = sroot3f(gm3[(ii*DN+jj)*DN+kk]);
    } else {
      order=4; int r = e-(NE1+NE2+NE3);
      int i=0; while (r >= H3f(DN-i)){ r -= H3f(DN-i); i++; }
      int j=i; while (r >= H2f(DN-j)){ r -= H2f(DN-j); j++; }
      int k=j; while (r >= DN-k){ r -= DN-k; k++; }
      ii=i; jj=j; kk=k; ll=k+r;
      tg = sroot4f(gm4[((ii*DN+jj)*DN+kk)*DN+ll]);
    }
  }

  __syncthreads();
  int pre[17]; pre[0]=0;
  #pragma unroll
  for (int p=0;p<16;p++) pre[p+1] = pre[p] + wcnt[p>>2][p&3];
  int cnt = pre[16];
  #pragma unroll
  for (int r=0;r<4;r++)
    if (match_r[r]) memb[pre[r*4+wave] + rank_r[r]] = r*256 + tid;

  const float* pA = &sx[ii][0];
  const float* pB = &sx[jj][0];
  const float* pC = &sx[kk][0];
  const float* pD = &sx[ll][0];

  float mom = 0.f;
  for (int base=0; base<cnt; base+=CH) {
    int m  = min(CH, cnt-base);
    int mp = (m+3)&~3;            // pad to float4 multiple
    __syncthreads();              // protects memb (1st iter) / previous chunk
    if (tid < m) {
      int b = memb[base + tid];
      const float4* er = (const float4*)(emb + b*DN);
      const float4* cr = (const float4*)(centers + c*DN);
      float4 e0=er[0], e1=er[1], e2=er[2], e3=er[3];
      float4 c0=cr[0], c1=cr[1], c2=cr[2], c3=cr[3];
      float v[16];
      v[0]=e0.x-c0.x; v[1]=e0.y-c0.y; v[2]=e0.z-c0.z; v[3]=e0.w-c0.w;
      v[4]=e1.x-c1.x; v[5]=e1.y-c1.y; v[6]=e1.z-c1.z; v[7]=e1.w-c1.w;
      v[8]=e2.x-c2.x; v[9]=e2.y-c2.y; v[10]=e2.z-c2.z; v[11]=e2.w-c2.w;
      v[12]=e3.x-c3.x; v[13]=e3.y-c3.y; v[14]=e3.z-c3.z; v[15]=e3.w-c3.w;
      #pragma unroll
      for (int i=0;i<DN;i++) sx[i][tid] = v[i];
    }
    if (tid < DN)                 // zero the float4 padding tail
      for (int n=m; n<mp; n++) sx[tid][n] = 0.f;
    __syncthreads();
    if (order==4) {
      for (int n=0; n<mp; n+=4) {
        float4 a=*(const float4*)(pA+n), b=*(const float4*)(pB+n);
        float4 cc=*(const float4*)(pC+n), d=*(const float4*)(pD+n);
        mom += a.x*b.x*cc.x*d.x + a.y*b.y*cc.y*d.y
             + a.z*b.z*cc.z*d.z + a.w*b.w*cc.w*d.w;
      }
    } else if (order==3) {
      for (int n=0; n<mp; n+=4) {
        float4 a=*(const float4*)(pA+n), b=*(const float4*)(pB+n);
        float4 cc=*(const float4*)(pC+n);
        mom += a.x*b.x*cc.x + a.y*b.y*cc.y + a.z*b.z*cc.z + a.w*b.w*cc.w;
      }
    } else if (order==2) {
      for (int n=0; n<mp; n+=4) {
        float4 a=*(const float4*)(pA+n), b=*(const float4*)(pB+n);
        mom += a.x*b.x + a.y*b.y + a.z*b.z + a.w*b.w;
      }
    } else if (order==1) {
      for (int n=0; n<mp; n+=4) {
        float4 a=*(const float4*)(pA+n);
        mom += a.x + a.y + a.z + a.w;
      }
    }
  }

  float contrib = 0.f;
  if (valid) {
    float mval = mom;
    if (order <= 2) mval /= ((float)cnt + EPSV);
    float v;
    if      (order==1) v = mval - tg;
    else if (order==2) v = sroot2f(mval) - tg;
    else if (order==3) v = sroot3f(mval) - tg;
    else               v = sroot4f(mval) - tg;
    float lw = (order==1)?1.f:(order==2)?0.5f:(order==3)?0.25f:0.125f;
    float cwn = (float)cnt * (1.f/1024.f);   // sum(cw) == B exactly
    contrib = lw * cwn * v * v;
  }

  // wave shuffle reduce (no syncs), then one atomic per block
  #pragma unroll
  for (int off=32; off; off>>=1) contrib += __shfl_down(contrib, off, 64);
  if (lane==0) wred[wave] = contrib;
  __syncthreads();
  if (tid==0) atomicAdd(out, wred[0]+wred[1]+wred[2]+wred[3]);
}

extern "C" void kernel_launch(void* const* d_in, const int* in_sizes, int n_in,
                              void* d_out, int out_size, void* d_ws, size_t ws_size,
                              hipStream_t stream) {
  const float* emb  = (const float*)d_in[0];   // [1024,16]
  const float* cen  = (const float*)d_in[1];   // [10,16]
  const float* logi = (const float*)d_in[2];   // [1024,10]
  const float* gm1  = (const float*)d_in[3];   // [16]
  const float* gm2  = (const float*)d_in[4];   // [16,16]
  const float* gm3  = (const float*)d_in[5];   // [16^3]
  const float* gm4  = (const float*)d_in[6];   // [16^4]
  // mw1..mw4 (d_in[7..10]) unused: mw[tuple] * #perms(tuple) == 1 exactly.

  hipMemsetAsync(d_out, 0, sizeof(float), stream);   // graph-capturable memset node
  kb<<<CN*EB, 256, 0, stream>>>(emb, cen, logi, gm1, gm2, gm3, gm4, (float*)d_out);
}